// Round 2
// baseline (272.668 us; speedup 1.0000x reference)
//
#include <hip/hip_runtime.h>
#include <hip/hip_bf16.h>

typedef __attribute__((ext_vector_type(8))) short short8;
typedef __attribute__((ext_vector_type(4))) float f32x4;

constexpr int B_ = 4, S_ = 2048, D_ = 512, H_ = 8, DP_ = 64;
constexpr int M_ = B_ * S_;  // 8192 rows

__device__ __forceinline__ unsigned short f2b(float f) {
    __hip_bfloat16 h = __float2bfloat16(f);
    return *reinterpret_cast<unsigned short*>(&h);
}

#define MFMA16(a, b, c) __builtin_amdgcn_mfma_f32_16x16x32_bf16((a), (b), (c), 0, 0, 0)

// ---------------- fp32 -> bf16 convert (x) ----------------
__global__ __launch_bounds__(256)
void convert_x(const float* __restrict__ in, unsigned short* __restrict__ out) {
    int i = blockIdx.x * 256 + threadIdx.x;   // one float4 per thread
    float4 v = ((const float4*)in)[i];
    ushort4 o;
    o.x = f2b(v.x); o.y = f2b(v.y); o.z = f2b(v.z); o.w = f2b(v.w);
    ((ushort4*)out)[i] = o;
}

// ---------------- weight transpose + convert: Wt[n][k] = bf16(W[k][n]) ----------------
__global__ __launch_bounds__(256)
void transpose_w(const float* __restrict__ w0, const float* __restrict__ w1,
                 const float* __restrict__ w2, const float* __restrict__ w3,
                 unsigned short* __restrict__ outw) {
    const float* in = (blockIdx.z == 0) ? w0 : (blockIdx.z == 1) ? w1
                     : (blockIdx.z == 2) ? w2 : w3;
    unsigned short* out = outw + (size_t)blockIdx.z * D_ * D_;
    __shared__ float t[64][65];
    int k0 = blockIdx.x * 64, n0 = blockIdx.y * 64;
    int tx = threadIdx.x & 63, ty = threadIdx.x >> 6;
#pragma unroll
    for (int i = 0; i < 16; i++) {
        int r = ty * 16 + i;
        t[r][tx] = in[(size_t)(k0 + r) * D_ + n0 + tx];
    }
    __syncthreads();
#pragma unroll
    for (int i = 0; i < 16; i++) {
        int r = ty * 16 + i;
        out[(size_t)(n0 + r) * D_ + k0 + tx] = f2b(t[tx][r]);
    }
}

// ---------------- QKV GEMM: [8192x512] @ W -> scatter to [B][H][S][64] ----------------
__global__ __launch_bounds__(256, 2)
void gemm_qkv(const unsigned short* __restrict__ X,
              const unsigned short* __restrict__ Wt,   // [3][512][512] transposed bf16
              unsigned short* __restrict__ QKV) {      // [3][B][H][S][64]
    const unsigned short* Bt = Wt + (size_t)blockIdx.z * D_ * D_;
    unsigned short* out = QKV + (size_t)blockIdx.z * M_ * D_;
    int m0 = blockIdx.x * 128, n0 = blockIdx.y * 128;
    int tid = threadIdx.x;
    int wave = tid >> 6, lane = tid & 63, l16 = lane & 15, quad = lane >> 4;
    int wm = (wave >> 1) * 64, wn = (wave & 1) * 64;

    __shared__ __align__(16) unsigned short As[128][40];
    __shared__ __align__(16) unsigned short Bs[128][40];

    f32x4 acc[4][4];
    const f32x4 zf = {0.f, 0.f, 0.f, 0.f};
#pragma unroll
    for (int i = 0; i < 4; i++)
#pragma unroll
        for (int j = 0; j < 4; j++) acc[i][j] = zf;

    for (int k0 = 0; k0 < D_; k0 += 32) {
        __syncthreads();
#pragma unroll
        for (int i = 0; i < 2; i++) {
            int c = tid + i * 256;
            int row = c >> 2, off = (c & 3) * 8;
            *(short8*)&As[row][off] = *(const short8*)(X + (size_t)(m0 + row) * D_ + k0 + off);
            *(short8*)&Bs[row][off] = *(const short8*)(Bt + (size_t)(n0 + row) * D_ + k0 + off);
        }
        __syncthreads();
        short8 af[4], bf[4];
#pragma unroll
        for (int mt = 0; mt < 4; mt++) af[mt] = *(const short8*)&As[wm + mt * 16 + l16][quad * 8];
#pragma unroll
        for (int nt = 0; nt < 4; nt++) bf[nt] = *(const short8*)&Bs[wn + nt * 16 + l16][quad * 8];
#pragma unroll
        for (int mt = 0; mt < 4; mt++)
#pragma unroll
            for (int nt = 0; nt < 4; nt++)
                acc[mt][nt] = MFMA16(af[mt], bf[nt], acc[mt][nt]);
    }
    // epilogue: C/D layout col=lane&15, row=quad*4+r; scatter to [B][H][S][64]
#pragma unroll
    for (int mt = 0; mt < 4; mt++)
#pragma unroll
        for (int nt = 0; nt < 4; nt++)
#pragma unroll
            for (int r = 0; r < 4; r++) {
                int m = m0 + wm + mt * 16 + quad * 4 + r;
                int n = n0 + wn + nt * 16 + l16;
                int bb = m >> 11, ss = m & 2047, hh = n >> 6, dd = n & 63;
                out[(((size_t)bb * H_ + hh) * S_ + ss) * DP_ + dd] = f2b(acc[mt][nt][r]);
            }
}

// ---------------- flash attention: per (b,h,64-q-rows) block ----------------
__global__ __launch_bounds__(256, 2)
void flash_attn(const unsigned short* __restrict__ Qg, const unsigned short* __restrict__ Kg,
                const unsigned short* __restrict__ Vg, unsigned short* __restrict__ ctx) {
    int bid = blockIdx.x;
    int qt = bid & 31, hh = (bid >> 5) & 7, bb = bid >> 8;
    int tid = threadIdx.x;
    int wave = tid >> 6, lane = tid & 63, l16 = lane & 15, quad = lane >> 4;

    size_t bh = ((size_t)bb * H_ + hh) * S_ * DP_;
    const unsigned short* Qb = Qg + bh;
    const unsigned short* Kb = Kg + bh;
    const unsigned short* Vb = Vg + bh;

    __shared__ __align__(16) unsigned short Vts[DP_][136];   // V^T [d][j], pad 8
    __shared__ __align__(16) unsigned short Ps[4][16][136];  // per-wave P

    // Q A-fragments held in registers for the whole kernel (K=64 -> 2 frags)
    short8 qf0, qf1;
    {
        const unsigned short* qp = Qb + (size_t)(qt * 64 + wave * 16 + l16) * DP_ + quad * 8;
        qf0 = *(const short8*)qp;
        qf1 = *(const short8*)(qp + 32);
    }

    const f32x4 zf = {0.f, 0.f, 0.f, 0.f};
    f32x4 oacc[4];
#pragma unroll
    for (int i = 0; i < 4; i++) oacc[i] = zf;
    float mrow[4], lrow[4];
#pragma unroll
    for (int r = 0; r < 4; r++) { mrow[r] = -1e30f; lrow[r] = 0.f; }
    constexpr float scale = 0.125f;  // 1/sqrt(64)

    for (int kv = 0; kv < S_; kv += 128) {
        __syncthreads();  // protect Vts from previous iteration's readers
        // stage V^T: 128 keys x 64 depth, coalesced read, scalar transposed LDS write
#pragma unroll
        for (int i = 0; i < 4; i++) {
            int c = tid + i * 256;
            int j = c >> 3, ch = c & 7;
            short8 v = *(const short8*)(Vb + (size_t)(kv + j) * DP_ + ch * 8);
#pragma unroll
            for (int e = 0; e < 8; e++) Vts[ch * 8 + e][j] = ((unsigned short*)&v)[e];
        }
        __syncthreads();

        // S = Q K^T : wave's 16 q-rows x 128 keys; K B-frags direct from global (L2-hot)
        f32x4 sacc[8];
#pragma unroll
        for (int nt = 0; nt < 8; nt++) {
            const unsigned short* kp = Kb + (size_t)(kv + nt * 16 + l16) * DP_ + quad * 8;
            short8 kf0 = *(const short8*)kp;
            short8 kf1 = *(const short8*)(kp + 32);
            f32x4 s = zf;
            s = MFMA16(qf0, kf0, s);
            s = MFMA16(qf1, kf1, s);
            sacc[nt] = s;
        }
        // online softmax (q-row = quad*4+r; 16 lanes sharing quad span the 128 cols)
        float alpha[4];
#pragma unroll
        for (int r = 0; r < 4; r++) {
            float mx = sacc[0][r];
#pragma unroll
            for (int nt = 1; nt < 8; nt++) mx = fmaxf(mx, sacc[nt][r]);
            mx *= scale;
#pragma unroll
            for (int off = 1; off < 16; off <<= 1) mx = fmaxf(mx, __shfl_xor(mx, off));
            float mn = fmaxf(mrow[r], mx);
            alpha[r] = __expf(mrow[r] - mn);
            mrow[r] = mn;
        }
        float rs[4] = {0.f, 0.f, 0.f, 0.f};
#pragma unroll
        for (int nt = 0; nt < 8; nt++)
#pragma unroll
            for (int r = 0; r < 4; r++) {
                float p = __expf(sacc[nt][r] * scale - mrow[r]);
                rs[r] += p;
                Ps[wave][quad * 4 + r][nt * 16 + l16] = f2b(p);
            }
#pragma unroll
        for (int r = 0; r < 4; r++) {
            float s = rs[r];
#pragma unroll
            for (int off = 1; off < 16; off <<= 1) s += __shfl_xor(s, off);
            lrow[r] = alpha[r] * lrow[r] + s;
        }
#pragma unroll
        for (int ot = 0; ot < 4; ot++)
#pragma unroll
            for (int r = 0; r < 4; r++) oacc[ot][r] *= alpha[r];
        // O += P V  (P via LDS layout-change: C-layout -> A-operand layout)
#pragma unroll
        for (int kt = 0; kt < 4; kt++) {
            short8 pf = *(const short8*)&Ps[wave][l16][kt * 32 + quad * 8];
#pragma unroll
            for (int ot = 0; ot < 4; ot++) {
                short8 vf = *(const short8*)&Vts[ot * 16 + l16][kt * 32 + quad * 8];
                oacc[ot] = MFMA16(pf, vf, oacc[ot]);
            }
        }
    }
    // epilogue: normalize, merge heads into [B][S][512]
#pragma unroll
    for (int ot = 0; ot < 4; ot++)
#pragma unroll
        for (int r = 0; r < 4; r++) {
            float o = oacc[ot][r] / lrow[r];
            int srow = qt * 64 + wave * 16 + quad * 4 + r;
            ctx[((size_t)bb * S_ + srow) * D_ + hh * DP_ + ot * 16 + l16] = f2b(o);
        }
}

// ---------------- output projection GEMM -> fp32 scratch ----------------
__global__ __launch_bounds__(256, 2)
void gemm_proj(const unsigned short* __restrict__ A,   // ctx [8192][512] bf16
               const unsigned short* __restrict__ Bt,  // Wo^T [512][512] bf16
               float* __restrict__ outf) {             // [8192][512] fp32
    int m0 = blockIdx.x * 128, n0 = blockIdx.y * 128;
    int tid = threadIdx.x;
    int wave = tid >> 6, lane = tid & 63, l16 = lane & 15, quad = lane >> 4;
    int wm = (wave >> 1) * 64, wn = (wave & 1) * 64;

    __shared__ __align__(16) unsigned short As[128][40];
    __shared__ __align__(16) unsigned short Bs[128][40];

    f32x4 acc[4][4];
    const f32x4 zf = {0.f, 0.f, 0.f, 0.f};
#pragma unroll
    for (int i = 0; i < 4; i++)
#pragma unroll
        for (int j = 0; j < 4; j++) acc[i][j] = zf;

    for (int k0 = 0; k0 < D_; k0 += 32) {
        __syncthreads();
#pragma unroll
        for (int i = 0; i < 2; i++) {
            int c = tid + i * 256;
            int row = c >> 2, off = (c & 3) * 8;
            *(short8*)&As[row][off] = *(const short8*)(A + (size_t)(m0 + row) * D_ + k0 + off);
            *(short8*)&Bs[row][off] = *(const short8*)(Bt + (size_t)(n0 + row) * D_ + k0 + off);
        }
        __syncthreads();
        short8 af[4], bf[4];
#pragma unroll
        for (int mt = 0; mt < 4; mt++) af[mt] = *(const short8*)&As[wm + mt * 16 + l16][quad * 8];
#pragma unroll
        for (int nt = 0; nt < 4; nt++) bf[nt] = *(const short8*)&Bs[wn + nt * 16 + l16][quad * 8];
#pragma unroll
        for (int mt = 0; mt < 4; mt++)
#pragma unroll
            for (int nt = 0; nt < 4; nt++)
                acc[mt][nt] = MFMA16(af[mt], bf[nt], acc[mt][nt]);
    }
#pragma unroll
    for (int mt = 0; mt < 4; mt++)
#pragma unroll
        for (int nt = 0; nt < 4; nt++)
#pragma unroll
            for (int r = 0; r < 4; r++) {
                int m = m0 + wm + mt * 16 + quad * 4 + r;
                int n = n0 + wn + nt * 16 + l16;
                outf[(size_t)m * D_ + n] = acc[mt][nt][r];
            }
}

// ---------------- bias + residual + LayerNorm (all fp32), one block per row ----------------
__global__ __launch_bounds__(256, 4)
void ln_out(const float* __restrict__ tmp, const float* __restrict__ Xg,
            const float* __restrict__ bo, const float* __restrict__ gamma,
            const float* __restrict__ beta, float* __restrict__ outp) {
    int row = blockIdx.x;
    int tid = threadIdx.x;
    int lane = tid & 63, wave = tid >> 6;
    float resid[2];
#pragma unroll
    for (int i = 0; i < 2; i++) {
        int c = tid + i * 256;
        resid[i] = Xg[(size_t)row * D_ + c] + tmp[(size_t)row * D_ + c] + bo[c];
    }
    float sum = resid[0] + resid[1];
    float sq = resid[0] * resid[0] + resid[1] * resid[1];
#pragma unroll
    for (int off = 1; off < 64; off <<= 1) {
        sum += __shfl_xor(sum, off);
        sq += __shfl_xor(sq, off);
    }
    __shared__ float red[8];
    if (lane == 0) { red[wave] = sum; red[4 + wave] = sq; }
    __syncthreads();
    sum = red[0] + red[1] + red[2] + red[3];
    sq = red[4] + red[5] + red[6] + red[7];
    float mu = sum * (1.0f / D_);
    float var = sq * (1.0f / D_) - mu * mu;
    float rstd = rsqrtf(var + 1e-6f);
#pragma unroll
    for (int i = 0; i < 2; i++) {
        int c = tid + i * 256;
        float o = (resid[i] - mu) * rstd * gamma[c] + beta[c];
        outp[(size_t)row * D_ + c] = o;
    }
}

extern "C" void kernel_launch(void* const* d_in, const int* in_sizes, int n_in,
                              void* d_out, int out_size, void* d_ws, size_t ws_size,
                              hipStream_t stream) {
    const float* x     = (const float*)d_in[0];
    const float* wq    = (const float*)d_in[1];
    const float* wk    = (const float*)d_in[2];
    const float* wv    = (const float*)d_in[3];
    const float* wo    = (const float*)d_in[4];
    const float* bo    = (const float*)d_in[5];
    const float* gamma = (const float*)d_in[6];
    const float* beta  = (const float*)d_in[7];
    float* out = (float*)d_out;

    // ws layout (bf16 elems unless noted), total 34 MB:
    //   [xb 8MB | wt 2MB | Q,K,V 24MB]
    //   ctx aliases xb (dead after gemm_qkv inputs consumed... precisely: xb dead after
    //   gemm_qkv; flash writes ctx there). fp32 tmp aliases Q/K/V (dead after flash).
    unsigned short* xb  = (unsigned short*)d_ws;                    // 8192*512 bf16
    unsigned short* wt  = xb + (size_t)M_ * D_;                     // 4*512*512 bf16
    unsigned short* Q   = wt + 4 * D_ * D_;
    unsigned short* K   = Q + (size_t)M_ * D_;
    unsigned short* V   = K + (size_t)M_ * D_;
    unsigned short* ctx = xb;                                       // alias: xb dead
    float* tmp = (float*)Q;                                         // alias: QKV dead

    convert_x<<<dim3(M_ * D_ / 4 / 256), 256, 0, stream>>>(x, xb);
    transpose_w<<<dim3(8, 8, 4), 256, 0, stream>>>(wq, wk, wv, wo, wt);
    gemm_qkv<<<dim3(64, 4, 3), 256, 0, stream>>>(xb, wt, Q);
    flash_attn<<<dim3(1024), 256, 0, stream>>>(Q, K, V, ctx);
    gemm_proj<<<dim3(64, 4), 256, 0, stream>>>(ctx, wt + 3 * D_ * D_, tmp);
    ln_out<<<dim3(8192), 256, 0, stream>>>(tmp, x, bo, gamma, beta, out);
}